// Round 6
// baseline (13720.499 us; speedup 1.0000x reference)
//
#include <hip/hip_runtime.h>
#include <hip/hip_bf16.h>

#define Tn 1024
#define Bn 128
#define INn 32
#define Hn 512
#define OUTn 32
#define Kn 64

typedef __attribute__((ext_vector_type(8))) __bf16 bf16x8;
typedef __attribute__((ext_vector_type(4))) float f32x4;
typedef __attribute__((ext_vector_type(2))) unsigned int u32x2;

typedef const __attribute__((address_space(1))) void* gas_p;
typedef __attribute__((address_space(3))) void* las_p;

static __device__ __forceinline__ float bf2f(unsigned short u) {
    union { unsigned int i; float f; } c; c.i = ((unsigned int)u) << 16; return c.f;
}
static __device__ __forceinline__ unsigned short f2bf(float f) {
    union { float f; unsigned int i; } c; c.f = f;
    unsigned int x = c.i;
    return (unsigned short)((x + 0x7fffu + ((x >> 16) & 1u)) >> 16);
}
static __device__ __forceinline__ float tanh_fast(float x) {
    float xc = fminf(fmaxf(x, -10.f), 10.f);
    float e = __expf(2.f * xc);
    return (e - 1.f) * __builtin_amdgcn_rcpf(e + 1.f);
}

// ---------------- f32 -> bf16 convert (n divisible by 4) ----------------
__global__ __launch_bounds__(256) void cvt_k(const float* __restrict__ in,
                                             unsigned short* __restrict__ out, int n4) {
    int i = blockIdx.x * 256 + threadIdx.x;
    if (i < n4) {
        float4 v = ((const float4*)in)[i];
        ushort4 o;
        o.x = f2bf(v.x); o.y = f2bf(v.y); o.z = f2bf(v.z); o.w = f2bf(v.w);
        ((ushort4*)out)[i] = o;
    }
}

// ---------------- pi coefficients + combined biases ----------------
__global__ __launch_bounds__(512) void prep_small(const float* __restrict__ b_d,
                                                  const float* __restrict__ bih0, const float* __restrict__ bhh0,
                                                  const float* __restrict__ bih1, const float* __restrict__ bhh1,
                                                  float* __restrict__ pi, float* __restrict__ bias0,
                                                  float* __restrict__ bias1) {
    int i = threadIdx.x;
    float d = 0.5f / (1.0f + expf(-b_d[i]));
    float c = 1.0f;
    for (int j = 1; j <= Kn; ++j) {
        c *= ((float)(j - 1) - d) / (float)j;
        pi[(j - 1) * Hn + i] = c;
    }
    bias0[i] = bih0[i] + bhh0[i];
    bias1[i] = bih1[i] + bhh1[i];
}

// ---------------- GEMM: C[M,N](bf16) = A[M,K](bf16) . Bm[N,K](bf16)^T + bias[N](f32) --------
__global__ __launch_bounds__(256, 2) void gemm_bt(const unsigned short* __restrict__ A,
                                                  const unsigned short* __restrict__ Bm,
                                                  unsigned short* __restrict__ C,
                                                  const float* __restrict__ bias,
                                                  int M, int N, int K) {
    __shared__ unsigned short As[128 * 32];
    __shared__ unsigned short Bs[128 * 32];
    int ntile = N >> 7;
    int bm = blockIdx.x / ntile;
    int bn = blockIdx.x - bm * ntile;
    size_t m0 = (size_t)bm << 7;
    int n0 = bn << 7;
    int tid = threadIdx.x;
    int lane = tid & 63, w = tid >> 6;
    int wm = w >> 1, wn = w & 1;
    int r = lane & 15, g = lane >> 4;
    int srow = tid >> 2, sblk = tid & 3;
    f32x4 acc[4][4] = {};
    for (int k0 = 0; k0 < K; k0 += 32) {
#pragma unroll
        for (int it = 0; it < 2; ++it) {
            const unsigned short* ga = A + (m0 + it * 64 + srow) * (size_t)K + k0 + sblk * 8;
            __builtin_amdgcn_global_load_lds((gas_p)ga, (las_p)((char*)As + it * 4096 + w * 1024), 16, 0, 0);
            const unsigned short* gbp = Bm + ((size_t)(n0 + it * 64 + srow)) * (size_t)K + k0 + sblk * 8;
            __builtin_amdgcn_global_load_lds((gas_p)gbp, (las_p)((char*)Bs + it * 4096 + w * 1024), 16, 0, 0);
        }
        __syncthreads();
        bf16x8 af[4], bfr[4];
#pragma unroll
        for (int m = 0; m < 4; ++m) af[m] = *(const bf16x8*)&As[(wm * 64 + m * 16 + r) * 32 + g * 8];
#pragma unroll
        for (int n = 0; n < 4; ++n) bfr[n] = *(const bf16x8*)&Bs[(wn * 64 + n * 16 + r) * 32 + g * 8];
#pragma unroll
        for (int m = 0; m < 4; ++m)
#pragma unroll
            for (int n = 0; n < 4; ++n)
                acc[m][n] = __builtin_amdgcn_mfma_f32_16x16x32_bf16(af[m], bfr[n], acc[m][n], 0, 0, 0);
        __syncthreads();
    }
#pragma unroll
    for (int n = 0; n < 4; ++n) {
        int col = n0 + wn * 64 + n * 16 + r;
        float bv = bias[col];
#pragma unroll
        for (int m = 0; m < 4; ++m) {
            size_t row0 = m0 + wm * 64 + m * 16 + g * 4;
#pragma unroll
            for (int q = 0; q < 4; ++q)
                C[(row0 + q) * (size_t)N + col] = f2bf(acc[m][n][q] + bv);
        }
    }
}

// ---------------- causal fractional-diff filter (chunked over t) ----------------
__global__ __launch_bounds__(256, 2) void filt_k(const unsigned short* __restrict__ X,
                                                 const float* __restrict__ Pi,
                                                 unsigned short* __restrict__ Y, int t_off) {
    int tid = threadIdx.x;
    int il = tid & 63, ts = tid >> 6;
    int i = blockIdx.x * 64 + il;
    int b = blockIdx.z;
    int tbase = t_off + blockIdx.y * 128 + ts * 32;
    float xr[96];
#pragma unroll
    for (int k2 = 0; k2 < 96; ++k2) {
        int t = tbase - 64 + k2;
        xr[k2] = (t >= 0) ? bf2f(X[(size_t)t * (Bn * Hn) + b * Hn + i]) : 0.0f;
    }
    float acc[32];
#pragma unroll
    for (int tt = 0; tt < 32; ++tt) acc[tt] = xr[64 + tt];
#pragma unroll
    for (int j = 1; j <= 64; ++j) {
        float p = Pi[(j - 1) * Hn + i];
#pragma unroll
        for (int tt = 0; tt < 32; ++tt) acc[tt] += p * xr[64 + tt - j];
    }
#pragma unroll
    for (int tt = 0; tt < 32; ++tt)
        Y[(size_t)(tbase - t_off + tt) * (Bn * Hn) + b * Hn + i] = f2bf(acc[tt]);
}

// ---------------- recurrence v5: W in registers, LDS-only h, swizzled, no vmcnt barrier ----
// 8 wgs (one per 16-batch group), 512 thr = 8 waves. Wave w owns o-rows [64w,64w+64):
// W slice 64x512 bf16 = 256 regs (unified VGPR/AGPR), loaded once, all indexing static.
// h double-buffered in LDS hl0/hl1 [16][512] u16 with 16B-chunk XOR swizzle (chunk^(r&7))
// applied on BOTH write and read (same involution) -> <=2-way banks. Barrier is
// lgkmcnt-only so pre prefetch loads + hs stores pipeline across steps.
// pre[t] prefetched 2 steps ahead into named scalars (pfA*/pfB*, t-loop unrolled x2).
// Layer 0 writes hs in place over pre (store row t vs loads rows >= t+2 of same elements).
__global__ __launch_bounds__(512, 1) void rec5_k(const unsigned short* __restrict__ W,
                                                 const unsigned short* pre,
                                                 unsigned short* hs,
                                                 float* __restrict__ hfin) {
    __shared__ unsigned short hl0[16 * 512];
    __shared__ unsigned short hl1[16 * 512];
    int gb = blockIdx.x;
    int tid = threadIdx.x, lane = tid & 63, w = tid >> 6;
    int r = lane & 15, g = lane >> 4;
    int ob = w * 64;
    bf16x8 wreg[4][16];
#pragma unroll
    for (int m = 0; m < 4; ++m)
#pragma unroll
        for (int kk = 0; kk < 16; ++kk)
            wreg[m][kk] = *(const bf16x8*)(W + (size_t)(ob + m * 16 + r) * Hn + kk * 32 + g * 8);
    int bb = gb * 16 + r;
    const unsigned short* preP = pre + (size_t)bb * Hn + ob + g * 4;
    unsigned short* hsP = hs ? hs + (size_t)bb * Hn + ob + g * 4 : (unsigned short*)0;
    // swizzled LDS offsets (u16 units). read: row r, chunk kk*4+g. write: chunk w*8+m*2+(g>>1).
    int rxor = r & 7;
    int rdbase = r * 512 + ((g ^ rxor) << 3);          // + ((kk*4)^0... kk*4 xor only touches high bits: (kk*4+g)^rxor
    // NOTE: (kk*4+g)^rxor != (kk*4)^rxor + g in general -> compute per kk below with full expr.
    unsigned long long pfA0, pfA1, pfA2, pfA3, pfB0, pfB1, pfB2, pfB3;
    pfA0 = *(const unsigned long long*)(preP);
    pfA1 = *(const unsigned long long*)(preP + 16);
    pfA2 = *(const unsigned long long*)(preP + 32);
    pfA3 = *(const unsigned long long*)(preP + 48);
    pfB0 = *(const unsigned long long*)(preP + (size_t)(Bn * Hn));
    pfB1 = *(const unsigned long long*)(preP + (size_t)(Bn * Hn) + 16);
    pfB2 = *(const unsigned long long*)(preP + (size_t)(Bn * Hn) + 32);
    pfB3 = *(const unsigned long long*)(preP + (size_t)(Bn * Hn) + 48);
    (void)rdbase;

#define REC_STEP(TT, HLR, HLW, P0, P1, P2, P3, ISLAST)                                          \
    {                                                                                           \
        int tn = (TT + 2 < Tn) ? TT + 2 : Tn - 1;                                               \
        unsigned long long n0 = *(const unsigned long long*)(preP + (size_t)tn * (Bn * Hn));    \
        unsigned long long n1 = *(const unsigned long long*)(preP + (size_t)tn * (Bn * Hn) + 16);\
        unsigned long long n2 = *(const unsigned long long*)(preP + (size_t)tn * (Bn * Hn) + 32);\
        unsigned long long n3 = *(const unsigned long long*)(preP + (size_t)tn * (Bn * Hn) + 48);\
        f32x4 acc0 = {0.f,0.f,0.f,0.f}, acc1 = {0.f,0.f,0.f,0.f};                               \
        f32x4 acc2 = {0.f,0.f,0.f,0.f}, acc3 = {0.f,0.f,0.f,0.f};                               \
        if (TT > 0) {                                                                           \
            _Pragma("unroll") for (int kk = 0; kk < 16; ++kk) {                                 \
                bf16x8 hb = *(const bf16x8*)&HLR[r * 512 + (((kk * 4 + g) ^ rxor) << 3)];       \
                acc0 = __builtin_amdgcn_mfma_f32_16x16x32_bf16(wreg[0][kk], hb, acc0, 0, 0, 0); \
                acc1 = __builtin_amdgcn_mfma_f32_16x16x32_bf16(wreg[1][kk], hb, acc1, 0, 0, 0); \
                acc2 = __builtin_amdgcn_mfma_f32_16x16x32_bf16(wreg[2][kk], hb, acc2, 0, 0, 0); \
                acc3 = __builtin_amdgcn_mfma_f32_16x16x32_bf16(wreg[3][kk], hb, acc3, 0, 0, 0); \
            }                                                                                   \
        }                                                                                       \
        union { unsigned long long u; unsigned short s[4]; } q0, q1, q2, q3;                    \
        q0.u = P0; q1.u = P1; q2.u = P2; q3.u = P3;                                             \
        float hv0 = tanh_fast(acc0[0] + bf2f(q0.s[0]));                                         \
        float hv1 = tanh_fast(acc0[1] + bf2f(q0.s[1]));                                         \
        float hv2 = tanh_fast(acc0[2] + bf2f(q0.s[2]));                                         \
        float hv3 = tanh_fast(acc0[3] + bf2f(q0.s[3]));                                         \
        float hv4 = tanh_fast(acc1[0] + bf2f(q1.s[0]));                                         \
        float hv5 = tanh_fast(acc1[1] + bf2f(q1.s[1]));                                         \
        float hv6 = tanh_fast(acc1[2] + bf2f(q1.s[2]));                                         \
        float hv7 = tanh_fast(acc1[3] + bf2f(q1.s[3]));                                         \
        float hv8 = tanh_fast(acc2[0] + bf2f(q2.s[0]));                                         \
        float hv9 = tanh_fast(acc2[1] + bf2f(q2.s[1]));                                         \
        float hva = tanh_fast(acc2[2] + bf2f(q2.s[2]));                                         \
        float hvb = tanh_fast(acc2[3] + bf2f(q2.s[3]));                                         \
        float hvc = tanh_fast(acc3[0] + bf2f(q3.s[0]));                                         \
        float hvd = tanh_fast(acc3[1] + bf2f(q3.s[1]));                                         \
        float hve = tanh_fast(acc3[2] + bf2f(q3.s[2]));                                         \
        float hvf = tanh_fast(acc3[3] + bf2f(q3.s[3]));                                         \
        unsigned int k0 = (unsigned)f2bf(hv0) | ((unsigned)f2bf(hv1) << 16);                    \
        unsigned int k1 = (unsigned)f2bf(hv2) | ((unsigned)f2bf(hv3) << 16);                    \
        unsigned int k2 = (unsigned)f2bf(hv4) | ((unsigned)f2bf(hv5) << 16);                    \
        unsigned int k3 = (unsigned)f2bf(hv6) | ((unsigned)f2bf(hv7) << 16);                    \
        unsigned int k4 = (unsigned)f2bf(hv8) | ((unsigned)f2bf(hv9) << 16);                    \
        unsigned int k5 = (unsigned)f2bf(hva) | ((unsigned)f2bf(hvb) << 16);                    \
        unsigned int k6 = (unsigned)f2bf(hvc) | ((unsigned)f2bf(hvd) << 16);                    \
        unsigned int k7 = (unsigned)f2bf(hve) | ((unsigned)f2bf(hvf) << 16);                    \
        int ws0 = r * 512 + (((w * 8 + 0 * 2 + (g >> 1)) ^ rxor) << 3) + ((g & 1) << 2);        \
        int ws1 = r * 512 + (((w * 8 + 1 * 2 + (g >> 1)) ^ rxor) << 3) + ((g & 1) << 2);        \
        int ws2 = r * 512 + (((w * 8 + 2 * 2 + (g >> 1)) ^ rxor) << 3) + ((g & 1) << 2);        \
        int ws3 = r * 512 + (((w * 8 + 3 * 2 + (g >> 1)) ^ rxor) << 3) + ((g & 1) << 2);        \
        { u32x2 v = {k0, k1}; *(u32x2*)&HLW[ws0] = v; }                                         \
        { u32x2 v = {k2, k3}; *(u32x2*)&HLW[ws1] = v; }                                         \
        { u32x2 v = {k4, k5}; *(u32x2*)&HLW[ws2] = v; }                                         \
        { u32x2 v = {k6, k7}; *(u32x2*)&HLW[ws3] = v; }                                         \
        if (hsP) {                                                                              \
            union { unsigned int u[2]; unsigned long long v; } o0, o1, o2, o3;                  \
            o0.u[0] = k0; o0.u[1] = k1; o1.u[0] = k2; o1.u[1] = k3;                             \
            o2.u[0] = k4; o2.u[1] = k5; o3.u[0] = k6; o3.u[1] = k7;                             \
            *(unsigned long long*)(hsP + (size_t)TT * (Bn * Hn))      = o0.v;                   \
            *(unsigned long long*)(hsP + (size_t)TT * (Bn * Hn) + 16) = o1.v;                   \
            *(unsigned long long*)(hsP + (size_t)TT * (Bn * Hn) + 32) = o2.v;                   \
            *(unsigned long long*)(hsP + (size_t)TT * (Bn * Hn) + 48) = o3.v;                   \
        }                                                                                       \
        if (ISLAST && hfin) {                                                                   \
            float* hf = hfin + (size_t)bb * Hn + ob + g * 4;                                    \
            hf[0]  = hv0; hf[1]  = hv1; hf[2]  = hv2; hf[3]  = hv3;                             \
            hf[16] = hv4; hf[17] = hv5; hf[18] = hv6; hf[19] = hv7;                             \
            hf[32] = hv8; hf[33] = hv9; hf[34] = hva; hf[35] = hvb;                             \
            hf[48] = hvc; hf[49] = hvd; hf[50] = hve; hf[51] = hvf;                             \
        }                                                                                       \
        P0 = n0; P1 = n1; P2 = n2; P3 = n3;                                                     \
        asm volatile("s_waitcnt lgkmcnt(0)\n\ts_barrier" ::: "memory");                         \
    }

    for (int t = 0; t < Tn; t += 2) {
        REC_STEP(t,     hl0, hl1, pfA0, pfA1, pfA2, pfA3, false)
        REC_STEP((t+1), hl1, hl0, pfB0, pfB1, pfB2, pfB3, (t + 1 == Tn - 1))
    }
#undef REC_STEP
}

// ---------------- final readout ----------------
__global__ __launch_bounds__(64) void readout_k(const float* __restrict__ hfin,
                                                const float* __restrict__ Who1,
                                                const float* __restrict__ bho1,
                                                float* __restrict__ out) {
    int b = blockIdx.x;
    __shared__ float hv[Hn];
    int tid = threadIdx.x;
    for (int i = tid; i < Hn; i += 64) hv[i] = hfin[(size_t)b * Hn + i];
    __syncthreads();
    if (tid < OUTn) {
        float acc = bho1[tid];
        const float* wrow = Who1 + (size_t)tid * Hn;
#pragma unroll 8
        for (int i = 0; i < Hn; ++i) acc += wrow[i] * hv[i];
        out[b * OUTn + tid] = acc;
    }
}

extern "C" void kernel_launch(void* const* d_in, const int* in_sizes, int n_in,
                              void* d_out, int out_size, void* d_ws, size_t ws_size,
                              hipStream_t stream) {
    const float* inputs = (const float*)d_in[0];
    const float* b_d    = (const float*)d_in[1];
    const float* W_emb  = (const float*)d_in[2];
    const float* b_emb  = (const float*)d_in[3];
    const float* W_ih0  = (const float*)d_in[4];
    const float* b_ih0  = (const float*)d_in[5];
    const float* W_hh0  = (const float*)d_in[6];
    const float* b_hh0  = (const float*)d_in[7];
    const float* W_ho0  = (const float*)d_in[8];
    const float* b_ho0  = (const float*)d_in[9];
    const float* W_ih1  = (const float*)d_in[10];
    const float* b_ih1  = (const float*)d_in[11];
    const float* W_hh1  = (const float*)d_in[12];
    const float* b_hh1  = (const float*)d_in[13];
    const float* W_ho1  = (const float*)d_in[14];
    const float* b_ho1  = (const float*)d_in[15];

    char* ws = (char*)d_ws;
    size_t off = 0;
    auto alloc = [&](size_t bytes) {
        void* p = ws + off;
        off += (bytes + 255) & ~(size_t)255;
        return p;
    };
    unsigned short* B    = (unsigned short*)alloc(134217728); // resident [T,B,H] bf16
    unsigned short* Hf   = (unsigned short*)alloc(67108864);  // half-T bounce
    unsigned short* inb  = (unsigned short*)alloc(8388608);
    unsigned short* Wemb = (unsigned short*)alloc(32768);
    unsigned short* Wih0 = (unsigned short*)alloc(524288);
    unsigned short* Whh0 = (unsigned short*)alloc(524288);
    unsigned short* Who0 = (unsigned short*)alloc(524288);
    unsigned short* Wih1 = (unsigned short*)alloc(524288);
    unsigned short* Whh1 = (unsigned short*)alloc(524288);
    float* bias0 = (float*)alloc(2048);
    float* bias1 = (float*)alloc(2048);
    float* piB   = (float*)alloc(131072);
    float* hfin  = (float*)alloc(262144);
    (void)ws_size; (void)in_sizes; (void)n_in; (void)out_size;

    unsigned short* B_hi = B + (size_t)512 * Bn * Hn;
    const size_t halfBytes = 67108864;
    const int Mh = 512 * Bn;

    cvt_k<<<4096, 256, 0, stream>>>(inputs, inb, 1048576);
    cvt_k<<<16,   256, 0, stream>>>(W_emb, Wemb, 4096);
    cvt_k<<<256,  256, 0, stream>>>(W_ih0, Wih0, 65536);
    cvt_k<<<256,  256, 0, stream>>>(W_hh0, Whh0, 65536);
    cvt_k<<<256,  256, 0, stream>>>(W_ho0, Who0, 65536);
    cvt_k<<<256,  256, 0, stream>>>(W_ih1, Wih1, 65536);
    cvt_k<<<256,  256, 0, stream>>>(W_hh1, Whh1, 65536);
    prep_small<<<1, 512, 0, stream>>>(b_d, b_ih0, b_hh0, b_ih1, b_hh1, piB, bias0, bias1);

    // ---- layer 0 ----
    gemm_bt<<<4096, 256, 0, stream>>>(inb, Wemb, B, b_emb, Tn * Bn, Hn, INn);    // B = x
    filt_k<<<dim3(8, 4, 128), 256, 0, stream>>>(B, piB, Hf, 512);
    gemm_bt<<<2048, 256, 0, stream>>>(Hf, Wih0, B_hi, bias0, Mh, Hn, Hn);        // B_hi = pre0_hi
    filt_k<<<dim3(8, 4, 128), 256, 0, stream>>>(B, piB, Hf, 0);
    gemm_bt<<<2048, 256, 0, stream>>>(Hf, Wih0, B, bias0, Mh, Hn, Hn);           // B_lo = pre0_lo
    rec5_k<<<8, 512, 0, stream>>>(Whh0, B, B, nullptr);                          // B = hs0 (in place)
    gemm_bt<<<2048, 256, 0, stream>>>(B_hi, Who0, Hf, b_ho0, Mh, Hn, Hn);
    hipMemcpyAsync(B_hi, Hf, halfBytes, hipMemcpyDeviceToDevice, stream);
    gemm_bt<<<2048, 256, 0, stream>>>(B, Who0, Hf, b_ho0, Mh, Hn, Hn);
    hipMemcpyAsync(B, Hf, halfBytes, hipMemcpyDeviceToDevice, stream);           // B = y0
    // ---- layer 1 ----
    filt_k<<<dim3(8, 4, 128), 256, 0, stream>>>(B, piB, Hf, 512);
    gemm_bt<<<2048, 256, 0, stream>>>(Hf, Wih1, B_hi, bias1, Mh, Hn, Hn);        // B_hi = pre1_hi
    filt_k<<<dim3(8, 4, 128), 256, 0, stream>>>(B, piB, Hf, 0);
    gemm_bt<<<2048, 256, 0, stream>>>(Hf, Wih1, B, bias1, Mh, Hn, Hn);           // B_lo = pre1_lo
    rec5_k<<<8, 512, 0, stream>>>(Whh1, B, nullptr, hfin);
    readout_k<<<128, 64, 0, stream>>>(hfin, W_ho1, b_ho1, (float*)d_out);
}

// Round 7
// 5597.309 us; speedup vs baseline: 2.4513x; 2.4513x over previous
//
#include <hip/hip_runtime.h>
#include <hip/hip_bf16.h>

#define Tn 1024
#define Bn 128
#define INn 32
#define Hn 512
#define OUTn 32
#define Kn 64
#define LPAD 536

typedef __attribute__((ext_vector_type(8))) __bf16 bf16x8;
typedef __attribute__((ext_vector_type(4))) float f32x4;
typedef __attribute__((ext_vector_type(4))) unsigned int u32x4;
typedef __attribute__((ext_vector_type(2))) unsigned int u32x2;

typedef const __attribute__((address_space(1))) void* gas_p;
typedef __attribute__((address_space(3))) void* las_p;

static __device__ __forceinline__ float bf2f(unsigned short u) {
    union { unsigned int i; float f; } c; c.i = ((unsigned int)u) << 16; return c.f;
}
static __device__ __forceinline__ unsigned short f2bf(float f) {
    union { float f; unsigned int i; } c; c.f = f;
    unsigned int x = c.i;
    return (unsigned short)((x + 0x7fffu + ((x >> 16) & 1u)) >> 16);
}
static __device__ __forceinline__ float tanh_fast(float x) {
    float xc = fminf(fmaxf(x, -10.f), 10.f);
    float e = __expf(2.f * xc);
    return (e - 1.f) * __builtin_amdgcn_rcpf(e + 1.f);
}

// ---------------- f32 -> bf16 convert (n divisible by 4) ----------------
__global__ __launch_bounds__(256) void cvt_k(const float* __restrict__ in,
                                             unsigned short* __restrict__ out, int n4) {
    int i = blockIdx.x * 256 + threadIdx.x;
    if (i < n4) {
        float4 v = ((const float4*)in)[i];
        ushort4 o;
        o.x = f2bf(v.x); o.y = f2bf(v.y); o.z = f2bf(v.z); o.w = f2bf(v.w);
        ((ushort4*)out)[i] = o;
    }
}

// ---------------- pi coefficients + combined biases ----------------
__global__ __launch_bounds__(512) void prep_small(const float* __restrict__ b_d,
                                                  const float* __restrict__ bih0, const float* __restrict__ bhh0,
                                                  const float* __restrict__ bih1, const float* __restrict__ bhh1,
                                                  float* __restrict__ pi, float* __restrict__ bias0,
                                                  float* __restrict__ bias1) {
    int i = threadIdx.x;
    float d = 0.5f / (1.0f + expf(-b_d[i]));
    float c = 1.0f;
    for (int j = 1; j <= Kn; ++j) {
        c *= ((float)(j - 1) - d) / (float)j;
        pi[(j - 1) * Hn + i] = c;
    }
    bias0[i] = bih0[i] + bhh0[i];
    bias1[i] = bih1[i] + bhh1[i];
}

// ---------------- GEMM: C[M,N](bf16) = A[M,K](bf16) . Bm[N,K](bf16)^T + bias[N](f32) --------
__global__ __launch_bounds__(256, 2) void gemm_bt(const unsigned short* __restrict__ A,
                                                  const unsigned short* __restrict__ Bm,
                                                  unsigned short* __restrict__ C,
                                                  const float* __restrict__ bias,
                                                  int M, int N, int K) {
    __shared__ unsigned short As[128 * 32];
    __shared__ unsigned short Bs[128 * 32];
    int ntile = N >> 7;
    int bm = blockIdx.x / ntile;
    int bn = blockIdx.x - bm * ntile;
    size_t m0 = (size_t)bm << 7;
    int n0 = bn << 7;
    int tid = threadIdx.x;
    int lane = tid & 63, w = tid >> 6;
    int wm = w >> 1, wn = w & 1;
    int r = lane & 15, g = lane >> 4;
    int srow = tid >> 2, sblk = tid & 3;
    f32x4 acc[4][4] = {};
    for (int k0 = 0; k0 < K; k0 += 32) {
#pragma unroll
        for (int it = 0; it < 2; ++it) {
            const unsigned short* ga = A + (m0 + it * 64 + srow) * (size_t)K + k0 + sblk * 8;
            __builtin_amdgcn_global_load_lds((gas_p)ga, (las_p)((char*)As + it * 4096 + w * 1024), 16, 0, 0);
            const unsigned short* gbp = Bm + ((size_t)(n0 + it * 64 + srow)) * (size_t)K + k0 + sblk * 8;
            __builtin_amdgcn_global_load_lds((gas_p)gbp, (las_p)((char*)Bs + it * 4096 + w * 1024), 16, 0, 0);
        }
        __syncthreads();
        bf16x8 af[4], bfr[4];
#pragma unroll
        for (int m = 0; m < 4; ++m) af[m] = *(const bf16x8*)&As[(wm * 64 + m * 16 + r) * 32 + g * 8];
#pragma unroll
        for (int n = 0; n < 4; ++n) bfr[n] = *(const bf16x8*)&Bs[(wn * 64 + n * 16 + r) * 32 + g * 8];
#pragma unroll
        for (int m = 0; m < 4; ++m)
#pragma unroll
            for (int n = 0; n < 4; ++n)
                acc[m][n] = __builtin_amdgcn_mfma_f32_16x16x32_bf16(af[m], bfr[n], acc[m][n], 0, 0, 0);
        __syncthreads();
    }
#pragma unroll
    for (int n = 0; n < 4; ++n) {
        int col = n0 + wn * 64 + n * 16 + r;
        float bv = bias[col];
#pragma unroll
        for (int m = 0; m < 4; ++m) {
            size_t row0 = m0 + wm * 64 + m * 16 + g * 4;
#pragma unroll
            for (int q = 0; q < 4; ++q)
                C[(row0 + q) * (size_t)N + col] = f2bf(acc[m][n][q] + bv);
        }
    }
}

// ---------------- causal fractional-diff filter (chunked over t) ----------------
__global__ __launch_bounds__(256, 2) void filt_k(const unsigned short* __restrict__ X,
                                                 const float* __restrict__ Pi,
                                                 unsigned short* __restrict__ Y, int t_off) {
    int tid = threadIdx.x;
    int il = tid & 63, ts = tid >> 6;
    int i = blockIdx.x * 64 + il;
    int b = blockIdx.z;
    int tbase = t_off + blockIdx.y * 128 + ts * 32;
    float xr[96];
#pragma unroll
    for (int k2 = 0; k2 < 96; ++k2) {
        int t = tbase - 64 + k2;
        xr[k2] = (t >= 0) ? bf2f(X[(size_t)t * (Bn * Hn) + b * Hn + i]) : 0.0f;
    }
    float acc[32];
#pragma unroll
    for (int tt = 0; tt < 32; ++tt) acc[tt] = xr[64 + tt];
#pragma unroll
    for (int j = 1; j <= 64; ++j) {
        float p = Pi[(j - 1) * Hn + i];
#pragma unroll
        for (int tt = 0; tt < 32; ++tt) acc[tt] += p * xr[64 + tt - j];
    }
#pragma unroll
    for (int tt = 0; tt < 32; ++tt)
        Y[(size_t)(tbase - t_off + tt) * (Bn * Hn) + b * Hn + i] = f2bf(acc[tt]);
}

// ---------------- recurrence v7: rec2 protocol + clean-vmem-queue poll ----------------
// 16 wgs: gb=bid&7 (16-batch group), go=bid>>3 (256-row o-half). 512 thr = 8 waves,
// wave owns 32 o-rows (wreg0/1[16] = 128 regs -- the proven-allocatable size).
// Step order: [barrier A] own-MFMA -> poll (vmem queue is ~empty: all other vmem
// was issued a full step ago) -> issue pre[t+2] prefetch -> scatter -> [barrier B,
// lgkm-only] partner-MFMA -> tanh -> publish sc1 (max partner lead) -> LDS own-half
// write -> hs stores. Tag-in-data ((bf16<<16)|step) exchange as in round 3; parity
// double-buffer overwrite-safe by the consume-before-publish chain; ex memset per
// launch kills stale tags across graph replays.
#define MFMA8(K0)                                                                              \
    {                                                                                          \
        _Pragma("unroll") for (int kk = 0; kk < 8; ++kk) {                                     \
            bf16x8 bf = *(const bf16x8*)(hrow + (K0 + kk) * 32 + g * 8);                       \
            acc0 = __builtin_amdgcn_mfma_f32_16x16x32_bf16(wreg0[K0 + kk], bf, acc0, 0, 0, 0); \
            acc1 = __builtin_amdgcn_mfma_f32_16x16x32_bf16(wreg1[K0 + kk], bf, acc1, 0, 0, 0); \
        }                                                                                      \
    }

__global__ __launch_bounds__(512, 2) void rec7_k(const unsigned short* __restrict__ W,
                                                 const unsigned short* pre,
                                                 unsigned short* hs,
                                                 float* __restrict__ hfin,
                                                 unsigned int* ex, int fbase) {
    __shared__ unsigned short hl[2][16][LPAD];
    int bid = blockIdx.x;
    int gb = bid & 7, go = bid >> 3;
    int tid = threadIdx.x, lane = tid & 63, w = tid >> 6;
    int r = lane & 15, g = lane >> 4;
    int ob = go * 256 + w * 32;
    bf16x8 wreg0[16], wreg1[16];
#pragma unroll
    for (int kk = 0; kk < 16; ++kk) {
        wreg0[kk] = *(const bf16x8*)(W + (size_t)(ob + r) * Hn + kk * 32 + g * 8);
        wreg1[kk] = *(const bf16x8*)(W + (size_t)(ob + 16 + r) * Hn + kk * 32 + g * 8);
    }
    int bb = gb * 16 + r;
    const unsigned short* preP = pre + (size_t)bb * Hn + ob + g * 4;
    unsigned short* hsP = hs ? hs + (size_t)bb * Hn + ob + g * 4 : (unsigned short*)0;
    int myblk = gb * 2 + go, pblk = gb * 2 + (go ^ 1);
    int pbatch = tid >> 5;
    int pcol = (go ^ 1) * 256 + (tid & 31) * 8;
    unsigned long long pfA0 = *(const unsigned long long*)(preP);
    unsigned long long pfA1 = *(const unsigned long long*)(preP + 16);
    unsigned long long pfB0 = *(const unsigned long long*)(preP + (size_t)(Bn * Hn));
    unsigned long long pfB1 = *(const unsigned long long*)(preP + (size_t)(Bn * Hn) + 16);

#define REC_STEP(TT, P0, P1, ISLAST)                                                             \
    {                                                                                            \
        asm volatile("s_waitcnt lgkmcnt(0)\n\ts_barrier" ::: "memory"); /* A: own half ready */  \
        f32x4 acc0 = {0.f, 0.f, 0.f, 0.f}, acc1 = {0.f, 0.f, 0.f, 0.f};                          \
        const unsigned short* hrow = &hl[TT & 1][r][0];                                          \
        if (TT > 0) {                                                                            \
            if (go == 0) MFMA8(0) else MFMA8(8)      /* phase 1: own half */                     \
            unsigned tg = (unsigned)(fbase + TT);                                                \
            const unsigned int* pp = ex + ((size_t)(TT & 1) * 16 + pblk) * 4096 + tid * 8;       \
            u32x4 a, b;                                                                          \
            while (1) {                                                                          \
                asm volatile("global_load_dwordx4 %0, %2, off sc1\n\t"                           \
                             "global_load_dwordx4 %1, %2, off offset:16 sc1\n\t"                 \
                             "s_waitcnt vmcnt(0)"                                                \
                             : "=v"(a), "=v"(b) : "v"(pp) : "memory");                           \
                bool ok = (a.x & 0xffffu) == tg && (a.y & 0xffffu) == tg &&                      \
                          (a.z & 0xffffu) == tg && (a.w & 0xffffu) == tg &&                      \
                          (b.x & 0xffffu) == tg && (b.y & 0xffffu) == tg &&                      \
                          (b.z & 0xffffu) == tg && (b.w & 0xffffu) == tg;                        \
                if (ok) break;                                                                   \
            }                                                                                    \
            unsigned int* ld = (unsigned int*)&hl[TT & 1][pbatch][pcol];                         \
            ld[0] = (a.x >> 16) | (a.y & 0xffff0000u);                                           \
            ld[1] = (a.z >> 16) | (a.w & 0xffff0000u);                                           \
            ld[2] = (b.x >> 16) | (b.y & 0xffff0000u);                                           \
            ld[3] = (b.z >> 16) | (b.w & 0xffff0000u);                                           \
        }                                                                                        \
        /* prefetch pre[TT+2] AFTER poll so next poll's vmcnt(0) finds a drained queue */        \
        int tn = (TT + 2 < Tn) ? TT + 2 : Tn - 1;                                                \
        unsigned long long n0 = *(const unsigned long long*)(preP + (size_t)tn * (Bn * Hn));     \
        unsigned long long n1 = *(const unsigned long long*)(preP + (size_t)tn * (Bn * Hn) + 16);\
        asm volatile("s_waitcnt lgkmcnt(0)\n\ts_barrier" ::: "memory"); /* B: partner ready */   \
        if (TT > 0) {                                                                            \
            if (go == 0) MFMA8(8) else MFMA8(0)      /* phase 2: partner half */                 \
        }                                                                                        \
        union { unsigned long long u; unsigned short s[4]; } p0, p1;                             \
        p0.u = P0; p1.u = P1;                                                                    \
        float h0 = tanh_fast(acc0[0] + bf2f(p0.s[0]));                                           \
        float h1 = tanh_fast(acc0[1] + bf2f(p0.s[1]));                                           \
        float h2 = tanh_fast(acc0[2] + bf2f(p0.s[2]));                                           \
        float h3 = tanh_fast(acc0[3] + bf2f(p0.s[3]));                                           \
        float h4 = tanh_fast(acc1[0] + bf2f(p1.s[0]));                                           \
        float h5 = tanh_fast(acc1[1] + bf2f(p1.s[1]));                                           \
        float h6 = tanh_fast(acc1[2] + bf2f(p1.s[2]));                                           \
        float h7 = tanh_fast(acc1[3] + bf2f(p1.s[3]));                                           \
        unsigned int b0 = f2bf(h0), b1 = f2bf(h1), b2 = f2bf(h2), b3 = f2bf(h3);                 \
        unsigned int b4 = f2bf(h4), b5 = f2bf(h5), b6 = f2bf(h6), b7 = f2bf(h7);                 \
        unsigned tv = (unsigned)(fbase + TT + 1);                                                \
        u32x4 s0 = { (b0 << 16) | tv, (b1 << 16) | tv, (b2 << 16) | tv, (b3 << 16) | tv };       \
        u32x4 s1 = { (b4 << 16) | tv, (b5 << 16) | tv, (b6 << 16) | tv, (b7 << 16) | tv };       \
        unsigned int* wp = ex + ((size_t)((TT + 1) & 1) * 16 + myblk) * 4096 + r * 256 + w * 32 + g * 4; \
        asm volatile("global_store_dwordx4 %0, %1, off sc1\n\t"                                  \
                     "global_store_dwordx4 %0, %2, off offset:64 sc1"                            \
                     :: "v"(wp), "v"(s0), "v"(s1) : "memory");                                   \
        {                                                                                        \
            u32x2 v0 = { b0 | (b1 << 16), b2 | (b3 << 16) };                                     \
            u32x2 v1 = { b4 | (b5 << 16), b6 | (b7 << 16) };                                     \
            *(u32x2*)&hl[(TT + 1) & 1][r][ob + g * 4] = v0;                                      \
            *(u32x2*)&hl[(TT + 1) & 1][r][ob + 16 + g * 4] = v1;                                 \
        }                                                                                        \
        if (hsP) {                                                                               \
            union { unsigned int u[2]; unsigned long long v; } o0, o1;                           \
            o0.u[0] = b0 | (b1 << 16); o0.u[1] = b2 | (b3 << 16);                                \
            o1.u[0] = b4 | (b5 << 16); o1.u[1] = b6 | (b7 << 16);                                \
            *(unsigned long long*)(hsP + (size_t)TT * (Bn * Hn)) = o0.v;                         \
            *(unsigned long long*)(hsP + (size_t)TT * (Bn * Hn) + 16) = o1.v;                    \
        }                                                                                        \
        if (ISLAST && hfin) {                                                                    \
            float* hf = hfin + (size_t)bb * Hn + ob + g * 4;                                     \
            hf[0] = h0; hf[1] = h1; hf[2] = h2; hf[3] = h3;                                      \
            hf[16] = h4; hf[17] = h5; hf[18] = h6; hf[19] = h7;                                  \
        }                                                                                        \
        P0 = n0; P1 = n1;                                                                        \
    }

    for (int t = 0; t < Tn; t += 2) {
        REC_STEP(t, pfA0, pfA1, false)
        REC_STEP((t + 1), pfB0, pfB1, (t + 1 == Tn - 1))
    }
#undef REC_STEP
}

// ---------------- final readout ----------------
__global__ __launch_bounds__(64) void readout_k(const float* __restrict__ hfin,
                                                const float* __restrict__ Who1,
                                                const float* __restrict__ bho1,
                                                float* __restrict__ out) {
    int b = blockIdx.x;
    __shared__ float hv[Hn];
    int tid = threadIdx.x;
    for (int i = tid; i < Hn; i += 64) hv[i] = hfin[(size_t)b * Hn + i];
    __syncthreads();
    if (tid < OUTn) {
        float acc = bho1[tid];
        const float* wrow = Who1 + (size_t)tid * Hn;
#pragma unroll 8
        for (int i = 0; i < Hn; ++i) acc += wrow[i] * hv[i];
        out[b * OUTn + tid] = acc;
    }
}

extern "C" void kernel_launch(void* const* d_in, const int* in_sizes, int n_in,
                              void* d_out, int out_size, void* d_ws, size_t ws_size,
                              hipStream_t stream) {
    const float* inputs = (const float*)d_in[0];
    const float* b_d    = (const float*)d_in[1];
    const float* W_emb  = (const float*)d_in[2];
    const float* b_emb  = (const float*)d_in[3];
    const float* W_ih0  = (const float*)d_in[4];
    const float* b_ih0  = (const float*)d_in[5];
    const float* W_hh0  = (const float*)d_in[6];
    const float* b_hh0  = (const float*)d_in[7];
    const float* W_ho0  = (const float*)d_in[8];
    const float* b_ho0  = (const float*)d_in[9];
    const float* W_ih1  = (const float*)d_in[10];
    const float* b_ih1  = (const float*)d_in[11];
    const float* W_hh1  = (const float*)d_in[12];
    const float* b_hh1  = (const float*)d_in[13];
    const float* W_ho1  = (const float*)d_in[14];
    const float* b_ho1  = (const float*)d_in[15];

    char* ws = (char*)d_ws;
    size_t off = 0;
    auto alloc = [&](size_t bytes) {
        void* p = ws + off;
        off += (bytes + 255) & ~(size_t)255;
        return p;
    };
    unsigned short* B    = (unsigned short*)alloc(134217728); // resident [T,B,H] bf16
    unsigned short* Hf   = (unsigned short*)alloc(67108864);  // half-T bounce
    unsigned short* inb  = (unsigned short*)alloc(8388608);
    unsigned short* Wemb = (unsigned short*)alloc(32768);
    unsigned short* Wih0 = (unsigned short*)alloc(524288);
    unsigned short* Whh0 = (unsigned short*)alloc(524288);
    unsigned short* Who0 = (unsigned short*)alloc(524288);
    unsigned short* Wih1 = (unsigned short*)alloc(524288);
    unsigned short* Whh1 = (unsigned short*)alloc(524288);
    float* bias0 = (float*)alloc(2048);
    float* bias1 = (float*)alloc(2048);
    float* piB   = (float*)alloc(131072);
    unsigned int* ex = (unsigned int*)alloc(524288);          // [2][16][16][256] u32
    float* hfin = (float*)alloc(262144);
    (void)ws_size; (void)in_sizes; (void)n_in; (void)out_size;

    unsigned short* B_hi = B + (size_t)512 * Bn * Hn;
    const size_t halfBytes = 67108864;
    const int Mh = 512 * Bn;

    hipMemsetAsync(ex, 0, 524288, stream);
    cvt_k<<<4096, 256, 0, stream>>>(inputs, inb, 1048576);
    cvt_k<<<16,   256, 0, stream>>>(W_emb, Wemb, 4096);
    cvt_k<<<256,  256, 0, stream>>>(W_ih0, Wih0, 65536);
    cvt_k<<<256,  256, 0, stream>>>(W_hh0, Whh0, 65536);
    cvt_k<<<256,  256, 0, stream>>>(W_ho0, Who0, 65536);
    cvt_k<<<256,  256, 0, stream>>>(W_ih1, Wih1, 65536);
    cvt_k<<<256,  256, 0, stream>>>(W_hh1, Whh1, 65536);
    prep_small<<<1, 512, 0, stream>>>(b_d, b_ih0, b_hh0, b_ih1, b_hh1, piB, bias0, bias1);

    // ---- layer 0 ----
    gemm_bt<<<4096, 256, 0, stream>>>(inb, Wemb, B, b_emb, Tn * Bn, Hn, INn);    // B = x
    filt_k<<<dim3(8, 4, 128), 256, 0, stream>>>(B, piB, Hf, 512);
    gemm_bt<<<2048, 256, 0, stream>>>(Hf, Wih0, B_hi, bias0, Mh, Hn, Hn);        // B_hi = pre0_hi
    filt_k<<<dim3(8, 4, 128), 256, 0, stream>>>(B, piB, Hf, 0);
    gemm_bt<<<2048, 256, 0, stream>>>(Hf, Wih0, B, bias0, Mh, Hn, Hn);           // B_lo = pre0_lo
    rec7_k<<<16, 512, 0, stream>>>(Whh0, B, B, nullptr, ex, 0);                  // B = hs0 (in place)
    gemm_bt<<<2048, 256, 0, stream>>>(B_hi, Who0, Hf, b_ho0, Mh, Hn, Hn);
    hipMemcpyAsync(B_hi, Hf, halfBytes, hipMemcpyDeviceToDevice, stream);
    gemm_bt<<<2048, 256, 0, stream>>>(B, Who0, Hf, b_ho0, Mh, Hn, Hn);
    hipMemcpyAsync(B, Hf, halfBytes, hipMemcpyDeviceToDevice, stream);           // B = y0
    // ---- layer 1 ----
    filt_k<<<dim3(8, 4, 128), 256, 0, stream>>>(B, piB, Hf, 512);
    gemm_bt<<<2048, 256, 0, stream>>>(Hf, Wih1, B_hi, bias1, Mh, Hn, Hn);        // B_hi = pre1_hi
    filt_k<<<dim3(8, 4, 128), 256, 0, stream>>>(B, piB, Hf, 0);
    gemm_bt<<<2048, 256, 0, stream>>>(Hf, Wih1, B, bias1, Mh, Hn, Hn);           // B_lo = pre1_lo
    rec7_k<<<16, 512, 0, stream>>>(Whh1, B, nullptr, hfin, ex, 1024);
    readout_k<<<128, 64, 0, stream>>>(hfin, W_ho1, b_ho1, (float*)d_out);
}